// Round 1
// baseline (505.352 us; speedup 1.0000x reference)
//
#include <hip/hip_runtime.h>
#include <hip/hip_bf16.h>
#include <stdint.h>

typedef short s16x8 __attribute__((ext_vector_type(8)));
typedef short s16x4 __attribute__((ext_vector_type(4)));
typedef float f32x4 __attribute__((ext_vector_type(4)));

#define MFMA16(a, b, c) __builtin_amdgcn_mfma_f32_16x16x32_bf16((a), (b), (c), 0, 0, 0)

__device__ __forceinline__ unsigned short f2bf(float f) {
  union { float f; uint32_t u; } x; x.f = f;
  uint32_t u = x.u;
  return (unsigned short)((u + 0x7FFFu + ((u >> 16) & 1u)) >> 16);
}
__device__ __forceinline__ float bf2f(unsigned short h) {
  union { uint32_t u; float f; } x; x.u = ((uint32_t)h) << 16;
  return x.f;
}

// ---------------- prep kernels ----------------
// ws layout: wt[4][192][192] bf16 (Wt[n][k] = W[k][n]), then rpb[6][64][64] bf16
__global__ __launch_bounds__(256) void prep_weights(
    const float* __restrict__ Wq, const float* __restrict__ Wk,
    const float* __restrict__ Wv, const float* __restrict__ Wp,
    unsigned short* __restrict__ wt) {
  int idx = blockIdx.x * 256 + threadIdx.x;
  if (idx >= 4 * 36864) return;
  int mat = idx / 36864, rem = idx % 36864;
  int n = rem / 192, k = rem % 192;
  const float* W = (mat == 0) ? Wq : (mat == 1) ? Wk : (mat == 2) ? Wv : Wp;
  wt[idx] = f2bf(W[k * 192 + n]);
}

__global__ __launch_bounds__(256) void prep_rpb(
    const float* __restrict__ bias_table, unsigned short* __restrict__ rpb) {
  int idx = blockIdx.x * 256 + threadIdx.x;
  if (idx >= 6 * 4096) return;
  int h = idx / 4096, r = idx % 4096;
  int i = r >> 6, j = r & 63;
  int dh = (i >> 3) - (j >> 3) + 7;
  int dw = (i & 7) - (j & 7) + 7;
  rpb[idx] = f2bf(bias_table[(dh * 15 + dw) * 6 + h]);
}

// ---------------- main fused kernel ----------------
#define XPAD 200   // 400B row stride: 16B aligned, 2-way bank alias (free)
#define VPAD 72    // 144B stride: 16B aligned, 2-way alias
#define PPAD 72
#define MPAD 66

struct Smem {
  unsigned short Xs[2][64][XPAD];   // X1/X2 staging; Xs[0] reused for X3, Xs[1] for O
  unsigned short Qs[64][XPAD];
  unsigned short Ks[64][XPAD];
  unsigned short VTs[192][VPAD];    // V transposed: [dim][token]
  unsigned short Ps[2][64][PPAD];   // per head-group P matrices
  unsigned short Ms[64][MPAD];      // mask window (bf16)
};

__global__ __launch_bounds__(512, 2) void win_attn(
    const float* __restrict__ X1g, const float* __restrict__ X2g,
    const float* __restrict__ X3g, const float* __restrict__ maskg,
    const float* __restrict__ bq, const float* __restrict__ bk,
    const float* __restrict__ bv, const float* __restrict__ bp,
    const unsigned short* __restrict__ wt, const unsigned short* __restrict__ rpb,
    float* __restrict__ out, int nW) {
  extern __shared__ char smem_raw[];
  Smem& S = *reinterpret_cast<Smem*>(smem_raw);
  const int b = blockIdx.x;
  const int tid = threadIdx.x;
  const int wave = tid >> 6, lane = tid & 63;
  const int l16 = lane & 15, lq = lane >> 4;
  const int mh = wave >> 2;   // projection m-half (2 m-tiles each)
  const int nh = wave & 3;    // projection n-quarter (3 n-tiles each)

  // ---- Phase A: stage X1,X2 -> LDS (bf16); X3 -> regs; mask -> LDS ----
  const float4* x1v = (const float4*)(X1g + (size_t)b * 12288);
  const float4* x2v = (const float4*)(X2g + (size_t)b * 12288);
  const float4* x3v = (const float4*)(X3g + (size_t)b * 12288);
  float4 x3r[6];
#pragma unroll
  for (int it = 0; it < 6; ++it) {
    int i = it * 512 + tid;          // 0..3071 (64 rows * 48 float4)
    float4 v1 = x1v[i];
    float4 v2 = x2v[i];
    x3r[it] = x3v[i];
    int row = i / 48, c = (i % 48) * 4;
    s16x4 p1, p2;
    p1[0] = (short)f2bf(v1.x); p1[1] = (short)f2bf(v1.y);
    p1[2] = (short)f2bf(v1.z); p1[3] = (short)f2bf(v1.w);
    p2[0] = (short)f2bf(v2.x); p2[1] = (short)f2bf(v2.y);
    p2[2] = (short)f2bf(v2.z); p2[3] = (short)f2bf(v2.w);
    *(s16x4*)&S.Xs[0][row][c] = p1;
    *(s16x4*)&S.Xs[1][row][c] = p2;
  }
  const float* mw = maskg + (size_t)(b % nW) * 4096;
  for (int i = tid; i < 4096; i += 512)
    S.Ms[i >> 6][i & 63] = f2bf(mw[i]);
  __syncthreads();

  // ---- projection helper: dst[64][192] = Xsrc[64][192] @ W + bias, *scale ----
  auto proj = [&](const unsigned short (*Xsrc)[XPAD], const unsigned short* W,
                  const float* bias, unsigned short (*dst)[XPAD], float scale) {
    s16x8 a[2][6];
#pragma unroll
    for (int mi = 0; mi < 2; ++mi)
#pragma unroll
      for (int ks = 0; ks < 6; ++ks)
        a[mi][ks] = *(const s16x8*)&Xsrc[(mh * 2 + mi) * 16 + l16][ks * 32 + lq * 8];
#pragma unroll
    for (int nt2 = 0; nt2 < 3; ++nt2) {
      int nt = nh * 3 + nt2;
      int col = nt * 16 + l16;
      float bsv = bias[col];
      f32x4 acc0 = {bsv, bsv, bsv, bsv};
      f32x4 acc1 = {bsv, bsv, bsv, bsv};
#pragma unroll
      for (int ks = 0; ks < 6; ++ks) {
        s16x8 bb = *(const s16x8*)&W[(size_t)col * 192 + ks * 32 + lq * 8];
        acc0 = MFMA16(a[0][ks], bb, acc0);
        acc1 = MFMA16(a[1][ks], bb, acc1);
      }
#pragma unroll
      for (int q = 0; q < 4; ++q) {
        dst[(mh * 2 + 0) * 16 + lq * 4 + q][col] = f2bf(acc0[q] * scale);
        dst[(mh * 2 + 1) * 16 + lq * 4 + q][col] = f2bf(acc1[q] * scale);
      }
    }
  };

  // ---- Phase B1: Q (scaled) and K projections ----
  proj(S.Xs[0], wt + 0 * 36864, bq, S.Qs, 0.17677669529663689f);  // 32^-0.5
  proj(S.Xs[1], wt + 1 * 36864, bk, S.Ks, 1.0f);
  __syncthreads();

  // ---- Phase B2: X3 regs -> Xs[0] ----
#pragma unroll
  for (int it = 0; it < 6; ++it) {
    int i = it * 512 + tid;
    int row = i / 48, c = (i % 48) * 4;
    s16x4 p3;
    p3[0] = (short)f2bf(x3r[it].x); p3[1] = (short)f2bf(x3r[it].y);
    p3[2] = (short)f2bf(x3r[it].z); p3[3] = (short)f2bf(x3r[it].w);
    *(s16x4*)&S.Xs[0][row][c] = p3;
  }
  __syncthreads();

  // ---- Phase B3: V projection, stored transposed VT[dim][tok] ----
  {
    const unsigned short* W = wt + 2 * 36864;
    s16x8 a[2][6];
#pragma unroll
    for (int mi = 0; mi < 2; ++mi)
#pragma unroll
      for (int ks = 0; ks < 6; ++ks)
        a[mi][ks] = *(const s16x8*)&S.Xs[0][(mh * 2 + mi) * 16 + l16][ks * 32 + lq * 8];
#pragma unroll
    for (int nt2 = 0; nt2 < 3; ++nt2) {
      int nt = nh * 3 + nt2;
      int col = nt * 16 + l16;    // dim index
      float bsv = bv[col];
      f32x4 acc0 = {bsv, bsv, bsv, bsv};
      f32x4 acc1 = {bsv, bsv, bsv, bsv};
#pragma unroll
      for (int ks = 0; ks < 6; ++ks) {
        s16x8 bb = *(const s16x8*)&W[(size_t)col * 192 + ks * 32 + lq * 8];
        acc0 = MFMA16(a[0][ks], bb, acc0);
        acc1 = MFMA16(a[1][ks], bb, acc1);
      }
      s16x4 pv0, pv1;
#pragma unroll
      for (int q = 0; q < 4; ++q) { pv0[q] = (short)f2bf(acc0[q]); pv1[q] = (short)f2bf(acc1[q]); }
      *(s16x4*)&S.VTs[col][(mh * 2 + 0) * 16 + lq * 4] = pv0;
      *(s16x4*)&S.VTs[col][(mh * 2 + 1) * 16 + lq * 4] = pv1;
    }
  }
  __syncthreads();

  // ---- Phase C: attention. wave -> (m-tile = wave&3, head-group = wave>>2) ----
  {
    const int mt = wave & 3, g = wave >> 2;
    const int row0 = mt * 16;
#pragma unroll 1
    for (int hh = 0; hh < 3; ++hh) {
      int h = g * 3 + hh;
      // QK^T : K = HEAD_DIM = 32 -> single MFMA k-step
      s16x8 qa = *(const s16x8*)&S.Qs[row0 + l16][h * 32 + lq * 8];
      f32x4 sv[4];
#pragma unroll
      for (int nt = 0; nt < 4; ++nt) {
        s16x8 kb = *(const s16x8*)&S.Ks[nt * 16 + l16][h * 32 + lq * 8];
        f32x4 z = {0.f, 0.f, 0.f, 0.f};
        sv[nt] = MFMA16(qa, kb, z);
      }
      // logits = S (Q pre-scaled) + rpb[h] + mask
      const unsigned short* rpbh = rpb + h * 4096;
      float lg[4][4];
#pragma unroll
      for (int nt = 0; nt < 4; ++nt) {
        int j = nt * 16 + l16;
#pragma unroll
        for (int q = 0; q < 4; ++q) {
          int i = row0 + lq * 4 + q;
          lg[nt][q] = sv[nt][q] + bf2f(rpbh[i * 64 + j]) + bf2f(S.Ms[i][j]);
        }
      }
      // wave-parallel softmax per row (16 lanes share a row; 4 cols each)
#pragma unroll
      for (int q = 0; q < 4; ++q) {
        float m = fmaxf(fmaxf(lg[0][q], lg[1][q]), fmaxf(lg[2][q], lg[3][q]));
#pragma unroll
        for (int s = 1; s < 16; s <<= 1) m = fmaxf(m, __shfl_xor(m, s, 64));
        float p[4], sum = 0.f;
#pragma unroll
        for (int nt = 0; nt < 4; ++nt) { p[nt] = __expf(lg[nt][q] - m); sum += p[nt]; }
#pragma unroll
        for (int s = 1; s < 16; s <<= 1) sum += __shfl_xor(sum, s, 64);
        float r = 1.0f / sum;
#pragma unroll
        for (int nt = 0; nt < 4; ++nt)
          S.Ps[g][row0 + lq * 4 + q][nt * 16 + l16] = f2bf(p[nt] * r);
      }
      // PV : [16,64] @ [64,32]
      f32x4 oacc[2] = {{0.f, 0.f, 0.f, 0.f}, {0.f, 0.f, 0.f, 0.f}};
#pragma unroll
      for (int kt = 0; kt < 2; ++kt) {
        s16x8 pa = *(const s16x8*)&S.Ps[g][row0 + l16][kt * 32 + lq * 8];
#pragma unroll
        for (int n2 = 0; n2 < 2; ++n2) {
          s16x8 vb = *(const s16x8*)&S.VTs[h * 32 + n2 * 16 + l16][kt * 32 + lq * 8];
          oacc[n2] = MFMA16(pa, vb, oacc[n2]);
        }
      }
      // O -> Xs[1] (X2 is dead)
#pragma unroll
      for (int n2 = 0; n2 < 2; ++n2)
#pragma unroll
        for (int q = 0; q < 4; ++q)
          S.Xs[1][row0 + lq * 4 + q][h * 32 + n2 * 16 + l16] = f2bf(oacc[n2][q]);
    }
  }
  __syncthreads();

  // ---- Phase D: out = O @ Wp + bp (fp32 to global) ----
  {
    const unsigned short* W = wt + 3 * 36864;
    float* ob = out + (size_t)b * 12288;
    s16x8 a[2][6];
#pragma unroll
    for (int mi = 0; mi < 2; ++mi)
#pragma unroll
      for (int ks = 0; ks < 6; ++ks)
        a[mi][ks] = *(const s16x8*)&S.Xs[1][(mh * 2 + mi) * 16 + l16][ks * 32 + lq * 8];
#pragma unroll
    for (int nt2 = 0; nt2 < 3; ++nt2) {
      int nt = nh * 3 + nt2;
      int col = nt * 16 + l16;
      float bsv = bp[col];
      f32x4 acc0 = {bsv, bsv, bsv, bsv};
      f32x4 acc1 = {bsv, bsv, bsv, bsv};
#pragma unroll
      for (int ks = 0; ks < 6; ++ks) {
        s16x8 bb = *(const s16x8*)&W[(size_t)col * 192 + ks * 32 + lq * 8];
        acc0 = MFMA16(a[0][ks], bb, acc0);
        acc1 = MFMA16(a[1][ks], bb, acc1);
      }
#pragma unroll
      for (int q = 0; q < 4; ++q) {
        ob[((mh * 2 + 0) * 16 + lq * 4 + q) * 192 + col] = acc0[q];
        ob[((mh * 2 + 1) * 16 + lq * 4 + q) * 192 + col] = acc1[q];
      }
    }
  }
}

extern "C" void kernel_launch(void* const* d_in, const int* in_sizes, int n_in,
                              void* d_out, int out_size, void* d_ws, size_t ws_size,
                              hipStream_t stream) {
  const float* X1 = (const float*)d_in[0];
  const float* X2 = (const float*)d_in[1];
  const float* X3 = (const float*)d_in[2];
  const float* mask = (const float*)d_in[3];
  const float* Wq = (const float*)d_in[4];
  const float* bq = (const float*)d_in[5];
  const float* Wk = (const float*)d_in[6];
  const float* bk = (const float*)d_in[7];
  const float* Wv = (const float*)d_in[8];
  const float* bv = (const float*)d_in[9];
  const float* Wp = (const float*)d_in[10];
  const float* bp = (const float*)d_in[11];
  const float* bt = (const float*)d_in[12];

  unsigned short* wt = (unsigned short*)d_ws;
  unsigned short* rpb = wt + 4 * 36864;

  int B_ = in_sizes[0] / 12288;
  int nW = in_sizes[3] / 4096;

  prep_weights<<<(4 * 36864 + 255) / 256, 256, 0, stream>>>(Wq, Wk, Wv, Wp, wt);
  prep_rpb<<<(6 * 4096 + 255) / 256, 256, 0, stream>>>(bt, rpb);

  (void)hipFuncSetAttribute((const void*)win_attn,
                            hipFuncAttributeMaxDynamicSharedMemorySize,
                            (int)sizeof(Smem));
  win_attn<<<B_, 512, sizeof(Smem), stream>>>(X1, X2, X3, mask, bq, bk, bv, bp,
                                              wt, rpb, (float*)d_out, nW);
}